// Round 1
// baseline (88.953 us; speedup 1.0000x reference)
//
#include <hip/hip_runtime.h>

// DirectNBodyAcceleration: N=8192 bodies, fp32.
// acc[j] = G * m_j * sum_i (y_i - y_j) * (||y_i - y_j||^2 + eps)^{-3/2}
// (reference's f[i,j] = G*masses[j]*inv_dist_cubed -> mass factors out of the sum;
//  i==j term is exactly zero since displacement is zero and eps > 0)

#define NB 8192
#define TILE 256
constexpr float EPS = 0.01f * 0.01f;  // softening_length^2

__global__ __launch_bounds__(256) void zero_kernel(float* __restrict__ out, int n) {
    int idx = blockIdx.x * 256 + threadIdx.x;
    if (idx < n) out[idx] = 0.0f;
}

__global__ __launch_bounds__(256) void nbody_kernel(
    const float* __restrict__ y,
    const float* __restrict__ masses,
    const float* __restrict__ Gp,
    float* __restrict__ out)
{
    __shared__ float4 sp[TILE];  // i-tile positions, w unused (alignment for ds_read_b128)

    const int tid = threadIdx.x;
    const int j   = blockIdx.x * TILE + tid;   // output body (always < NB: grid exact)
    const int i0  = blockIdx.y * TILE;         // start of i-tile

    const float xj = y[3 * j + 0];
    const float yj = y[3 * j + 1];
    const float zj = y[3 * j + 2];

    // Stage i-tile into LDS. 256 threads each read 3 consecutive floats
    // (contiguous 3 KB region overall).
    {
        const float* src = y + 3 * i0;
        sp[tid] = make_float4(src[3 * tid + 0], src[3 * tid + 1], src[3 * tid + 2], 0.0f);
    }
    __syncthreads();

    float ax = 0.0f, ay = 0.0f, az = 0.0f;
#pragma unroll 8
    for (int ii = 0; ii < TILE; ++ii) {
        float4 p = sp[ii];                     // broadcast ds_read_b128, conflict-free
        float dx = p.x - xj;
        float dy = p.y - yj;
        float dz = p.z - zj;
        float r2 = fmaf(dx, dx, fmaf(dy, dy, fmaf(dz, dz, EPS)));
        float rinv  = rsqrtf(r2);              // v_rsq_f32
        float rinv3 = rinv * rinv * rinv;      // (r2+eps)^{-3/2}
        ax = fmaf(dx, rinv3, ax);
        ay = fmaf(dy, rinv3, ay);
        az = fmaf(dz, rinv3, az);
    }

    const float s = Gp[0] * masses[j];         // receiver mass * G factors out
    atomicAdd(&out[3 * j + 0], ax * s);        // 32 blocks accumulate per j
    atomicAdd(&out[3 * j + 1], ay * s);
    atomicAdd(&out[3 * j + 2], az * s);
}

extern "C" void kernel_launch(void* const* d_in, const int* in_sizes, int n_in,
                              void* d_out, int out_size, void* d_ws, size_t ws_size,
                              hipStream_t stream) {
    // inputs: t (unused), y [N,3], masses [N], G [1]
    const float* y      = (const float*)d_in[1];
    const float* masses = (const float*)d_in[2];
    const float* Gp     = (const float*)d_in[3];
    float* out = (float*)d_out;

    // d_out is poisoned to 0xAA before every launch -> zero it first (same stream).
    zero_kernel<<<(3 * NB + 255) / 256, 256, 0, stream>>>(out, 3 * NB);

    dim3 grid(NB / TILE, NB / TILE);  // 32 x 32 = 1024 blocks
    nbody_kernel<<<grid, 256, 0, stream>>>(y, masses, Gp, out);
}